// Round 3
// baseline (274.360 us; speedup 1.0000x reference)
//
#include <hip/hip_runtime.h>

// BoundaryAwareLoss: masked, boundary-weighted BCE over instance channels {1,3,5,7}
// of logits/targets (2,8,128,128,128) fp32.
// 2x 6-neighbor erosion == one erosion by the Manhattan-radius-2 ball (25 pts),
// zero-padded. Targets are binary -> bit-packed erosion (branchless, register-only).
// v3: 2 dispatches total — pack (+ws zero) and main (+last-block finalize).

#define DD 128
#define HH 128
#define WW 128
#define HW_ (HH * WW)
#define DHW (DD * HH * WW)

typedef unsigned long long ull;

#define MAIN_GX 128
#define TOTAL_MAIN_BLOCKS (MAIN_GX * 8)

// ws layout (doubles): ws[0]=sum(bce), ws[1]=sum(n); ((uint*)ws)[4] = ticket
// packed bits at byte offset 256.

// ---------------- pass 1: pack targets (active channels) to 1 bit/voxel ----------------
// pk layout: pk[ch*32768 + row*2 + h], row = z*128+y, h selects x in [64h, 64h+64)
__global__ void __launch_bounds__(256) bal_pack(const float* __restrict__ targets,
                                                const int*   __restrict__ mask,
                                                ull*         __restrict__ pk,
                                                double*      __restrict__ ws)
{
    // one block zeroes the accumulators + ticket (visible to bal_main via the
    // inter-dispatch barrier; atomics are belt-and-braces for XCD coherence)
    if (blockIdx.x == 0 && blockIdx.y == 0 && threadIdx.x == 0) {
        atomicExch((ull*)&ws[0], 0ull);
        atomicExch((ull*)&ws[1], 0ull);
        atomicExch(&((unsigned int*)ws)[4], 0u);
    }

    const int ch = blockIdx.y;           // 0..7
    const int b  = ch >> 2;
    const int c  = (ch & 3) * 2 + 1;     // instance channels 1,3,5,7
    if (mask[b * 8 + c] == 0) return;

    const int tid = threadIdx.x;
    const size_t blockbase = (size_t)blockIdx.x * 1024;   // voxels
    const float* tg = targets + (size_t)(b * 8 + c) * DHW + blockbase;

    float4 t4 = *(const float4*)(tg + tid * 4);
    unsigned nib = (unsigned)(t4.x > 0.5f)
                 | ((unsigned)(t4.y > 0.5f) << 1)
                 | ((unsigned)(t4.z > 0.5f) << 2)
                 | ((unsigned)(t4.w > 0.5f) << 3);
    ull v = ((ull)nib) << ((tid & 15) * 4);
    // OR-combine nibbles across each aligned group of 16 lanes -> one u64 (64 voxels)
    v |= __shfl_xor(v, 1);
    v |= __shfl_xor(v, 2);
    v |= __shfl_xor(v, 4);
    v |= __shfl_xor(v, 8);
    if ((tid & 15) == 0)
        pk[(size_t)ch * 32768 + (blockbase >> 6) + (tid >> 4)] = v;
}

// ---------------- pass 2: erosion (bitwise) + BCE + reduction + finalize ----------------
__device__ __forceinline__ void ld_row(const ull* __restrict__ pch, int zz, int yy,
                                       ull& a0, ull& a1)
{
    if (((unsigned)zz < 128u) & ((unsigned)yy < 128u)) {
        const ull* p = pch + (((zz << 7) + yy) << 1);
        a0 = p[0];
        a1 = p[1];
    } else {
        a0 = 0ull;
        a1 = 0ull;
    }
}

__global__ void __launch_bounds__(256) bal_main(const float* __restrict__ logits,
                                                const float* __restrict__ spatial,
                                                const int*   __restrict__ mask,
                                                const ull*   __restrict__ pk,
                                                double*      __restrict__ ws,
                                                float*       __restrict__ out)
{
    const int ch = blockIdx.y;
    const int b  = ch >> 2;
    const int c  = (ch & 3) * 2 + 1;
    const int tid = threadIdx.x;
    const bool active = (mask[b * 8 + c] != 0);

    if (active) {
        const int half = blockIdx.x * 256 + tid;   // 0..32767 half-rows (64 voxels each)
        const int row  = half >> 1;
        const int h    = half & 1;
        const int y    = row & 127;
        const int z    = row >> 7;
        const ull* pch = pk + (size_t)ch * 32768;

        // ---- branchless 25-pt erosion on 128-bit rows ----
        ull c0, c1;
        ld_row(pch, z, y, c0, c1);
        // center row: x-erosion radius 2
        ull elo = c0 & ((c0 >> 1) | (c1 << 63)) & (c0 << 1)
                     & ((c0 >> 2) | (c1 << 62)) & (c0 << 2);
        ull ehi = c1 & (c1 >> 1) & ((c1 << 1) | (c0 >> 63))
                     & (c1 >> 2) & ((c1 << 2) | (c0 >> 62));
        // Manhattan-dist-1 rows: radius 1
        {
            ull a0, a1;
            ld_row(pch, z - 1, y, a0, a1);
            elo &= a0 & ((a0 >> 1) | (a1 << 63)) & (a0 << 1);
            ehi &= a1 & (a1 >> 1) & ((a1 << 1) | (a0 >> 63));
            ld_row(pch, z + 1, y, a0, a1);
            elo &= a0 & ((a0 >> 1) | (a1 << 63)) & (a0 << 1);
            ehi &= a1 & (a1 >> 1) & ((a1 << 1) | (a0 >> 63));
            ld_row(pch, z, y - 1, a0, a1);
            elo &= a0 & ((a0 >> 1) | (a1 << 63)) & (a0 << 1);
            ehi &= a1 & (a1 >> 1) & ((a1 << 1) | (a0 >> 63));
            ld_row(pch, z, y + 1, a0, a1);
            elo &= a0 & ((a0 >> 1) | (a1 << 63)) & (a0 << 1);
            ehi &= a1 & (a1 >> 1) & ((a1 << 1) | (a0 >> 63));
        }
        // Manhattan-dist-2 rows: radius 0
        {
            ull a0, a1;
            ld_row(pch, z - 2, y,     a0, a1); elo &= a0; ehi &= a1;
            ld_row(pch, z + 2, y,     a0, a1); elo &= a0; ehi &= a1;
            ld_row(pch, z,     y - 2, a0, a1); elo &= a0; ehi &= a1;
            ld_row(pch, z,     y + 2, a0, a1); elo &= a0; ehi &= a1;
            ld_row(pch, z - 1, y - 1, a0, a1); elo &= a0; ehi &= a1;
            ld_row(pch, z - 1, y + 1, a0, a1); elo &= a0; ehi &= a1;
            ld_row(pch, z + 1, y - 1, a0, a1); elo &= a0; ehi &= a1;
            ld_row(pch, z + 1, y + 1, a0, a1); elo &= a0; ehi &= a1;
        }
        const ull ero   = h ? ehi : elo;
        const ull tbits = h ? c1  : c0;

        // ---- BCE: wave-cooperative, fully coalesced float4 streaming ----
        const int wave = tid >> 6;
        const int lane = tid & 63;
        const float* lg = logits  + (size_t)(b * 8 + c) * DHW;
        const float* sp = spatial + (size_t)b * DHW;
        const int    waveHalfBase = blockIdx.x * 256 + wave * 64;
        const size_t vbase        = (size_t)waveHalfBase * 64;

        float acc = 0.0f, n = 0.0f;
        #pragma unroll 4
        for (int m = 0; m < 16; ++m) {
            const int q   = 4 * m + (lane >> 4);   // half-row (within wave) this lane serves
            const ull er  = __shfl(ero, q);
            const ull tb  = __shfl(tbits, q);
            const int sh  = (lane & 15) * 4;
            const unsigned eb  = (unsigned)(er >> sh) & 0xFu;
            const unsigned tbn = (unsigned)(tb >> sh) & 0xFu;
            const size_t voff = vbase + (size_t)q * 64 + sh;   // == vbase + 256*m + lane*4
            const float4 l4 = *(const float4*)(lg + voff);
            const float4 s4 = *(const float4*)(sp + voff);
            #define PROC(LV, SV, TB, EB)                                              \
            {                                                                         \
                const float tf = (float)(TB);                                         \
                const float w  = fmaf(4.0f, tf - (float)(EB), 1.0f);                  \
                const float a  = fabsf(LV);                                           \
                const float u  = __builtin_amdgcn_exp2f(a * -1.4426950408889634f);    \
                const float so = __builtin_amdgcn_logf(1.0f + u) * 0.6931471805599453f;\
                const float bce = fmaxf(LV, 0.0f) - (LV) * tf + so;                   \
                acc = fmaf((SV) * w, bce, acc);                                       \
                n += (SV);                                                            \
            }
            PROC(l4.x, s4.x, tbn & 1u,        eb & 1u)
            PROC(l4.y, s4.y, (tbn >> 1) & 1u, (eb >> 1) & 1u)
            PROC(l4.z, s4.z, (tbn >> 2) & 1u, (eb >> 2) & 1u)
            PROC(l4.w, s4.w, (tbn >> 3) & 1u, (eb >> 3) & 1u)
            #undef PROC
        }

        // wave (64-lane) shuffle reduction
        #pragma unroll
        for (int o = 32; o > 0; o >>= 1) {
            acc += __shfl_down(acc, o);
            n   += __shfl_down(n, o);
        }
        __shared__ float sb[4], sn[4];
        if (lane == 0) { sb[wave] = acc; sn[wave] = n; }
        __syncthreads();
        if (tid == 0) {
            atomicAdd(&ws[0], (double)(sb[0] + sb[1] + sb[2] + sb[3]));
            atomicAdd(&ws[1], (double)(sn[0] + sn[1] + sn[2] + sn[3]));
        }
    }

    // ---- last-block finalize (every block, masked or not, takes a ticket) ----
    if (tid == 0) {
        __threadfence();   // make my sum atomics ordered before the ticket
        unsigned prev = atomicAdd(&((unsigned int*)ws)[4], 1u);
        if (prev == TOTAL_MAIN_BLOCKS - 1) {
            __threadfence();
            const double s = atomicAdd(&ws[0], 0.0);   // atomic read (coherence point)
            const double n = atomicAdd(&ws[1], 0.0);
            out[0] = (n > 0.0) ? (float)(s / (n < 1.0 ? 1.0 : n)) : 0.0f;
        }
    }
}

// ---------------- fallback (ws too small): round-1 direct kernel ----------------
__device__ __constant__ signed char OFFS[24][3] = {
    {-1,0,0},{1,0,0},{0,-1,0},{0,1,0},{0,0,-1},{0,0,1},
    {-2,0,0},{2,0,0},{0,-2,0},{0,2,0},{0,0,-2},{0,0,2},
    {-1,-1,0},{-1,1,0},{1,-1,0},{1,1,0},
    {-1,0,-1},{-1,0,1},{1,0,-1},{1,0,1},
    {0,-1,-1},{0,-1,1},{0,1,-1},{0,1,1}
};

__global__ void __launch_bounds__(256) bal_direct(
    const float* __restrict__ logits, const float* __restrict__ targets,
    const int* __restrict__ mask, const float* __restrict__ spatial,
    double* __restrict__ ws)
{
    const int ch = blockIdx.y;
    const int b  = ch >> 2;
    const int c  = 2 * (ch & 3) + 1;
    if (mask[b * 8 + c] == 0) return;
    const float* lg = logits  + (size_t)(b * 8 + c) * DHW;
    const float* tg = targets + (size_t)(b * 8 + c) * DHW;
    const float* sp = spatial + (size_t)b * DHW;
    const int tid = threadIdx.x;
    const int row = blockIdx.x * 8 + (tid >> 5);
    const int x0  = (tid & 31) * 4;
    const int z   = row >> 7;
    const int y   = row & 127;
    const size_t off = (size_t)row * WW + x0;
    float4 s4 = *(const float4*)(sp + off);
    float n_local   = s4.x + s4.y + s4.z + s4.w;
    float bce_local = 0.0f;
    if (n_local > 0.0f) {
        float4 l4 = *(const float4*)(lg + off);
        float4 t4 = *(const float4*)(tg + off);
        const float sv[4] = {s4.x, s4.y, s4.z, s4.w};
        const float lv[4] = {l4.x, l4.y, l4.z, l4.w};
        const float tv[4] = {t4.x, t4.y, t4.z, t4.w};
        #pragma unroll
        for (int j = 0; j < 4; ++j) {
            if (sv[j] == 0.0f) continue;
            const float l = lv[j];
            const float t = tv[j];
            float bce = fmaxf(l, 0.0f) - l * t + log1pf(expf(-fabsf(l)));
            float w = 1.0f;
            if (t > 0.5f) {
                float e = 1.0f;
                const int x = x0 + j;
                for (int k = 0; k < 24; ++k) {
                    const int zz = z + OFFS[k][0];
                    const int yy = y + OFFS[k][1];
                    const int xx = x + OFFS[k][2];
                    float v = 0.0f;
                    if (((unsigned)zz < 128u) & ((unsigned)yy < 128u) & ((unsigned)xx < 128u))
                        v = tg[zz * HW_ + yy * WW + xx];
                    if (v < 0.5f) { e = 0.0f; break; }
                }
                w = 1.0f + 4.0f * (1.0f - e);
            }
            bce_local += bce * w;
        }
    }
    #pragma unroll
    for (int o = 32; o > 0; o >>= 1) {
        bce_local += __shfl_down(bce_local, o);
        n_local   += __shfl_down(n_local, o);
    }
    __shared__ float sb[4], sn[4];
    const int wave = tid >> 6;
    if ((tid & 63) == 0) { sb[wave] = bce_local; sn[wave] = n_local; }
    __syncthreads();
    if (tid == 0) {
        atomicAdd(&ws[0], (double)(sb[0] + sb[1] + sb[2] + sb[3]));
        atomicAdd(&ws[1], (double)(sn[0] + sn[1] + sn[2] + sn[3]));
    }
}

__global__ void bal_finalize(const double* __restrict__ ws, float* __restrict__ out)
{
    const double s = ws[0];
    const double n = ws[1];
    out[0] = (n > 0.0) ? (float)(s / (n < 1.0 ? 1.0 : n)) : 0.0f;
}

extern "C" void kernel_launch(void* const* d_in, const int* in_sizes, int n_in,
                              void* d_out, int out_size, void* d_ws, size_t ws_size,
                              hipStream_t stream)
{
    const float* logits  = (const float*)d_in[0];
    const float* targets = (const float*)d_in[1];
    const int*   mask    = (const int*)d_in[2];
    const float* spatial = (const float*)d_in[3];
    double* ws = (double*)d_ws;

    const size_t need = 256 + (size_t)8 * 32768 * sizeof(ull);   // sums+ticket pad, 2 MB bits
    if (ws_size >= need) {
        ull* pk = (ull*)((char*)d_ws + 256);
        bal_pack<<<dim3(2048, 8), 256, 0, stream>>>(targets, mask, pk, ws);
        bal_main<<<dim3(MAIN_GX, 8), 256, 0, stream>>>(logits, spatial, mask, pk, ws,
                                                       (float*)d_out);
    } else {
        hipMemsetAsync(d_ws, 0, 16, stream);
        bal_direct<<<dim3(2048, 8), 256, 0, stream>>>(logits, targets, mask, spatial, ws);
        bal_finalize<<<1, 1, 0, stream>>>(ws, (float*)d_out);
    }
}

// Round 4
// 255.113 us; speedup vs baseline: 1.0754x; 1.0754x over previous
//
#include <hip/hip_runtime.h>

// BoundaryAwareLoss: masked, boundary-weighted BCE over instance channels {1,3,5,7}
// of logits/targets (2,8,128,128,128) fp32.
// 2x 6-neighbor erosion == one erosion by the Manhattan-radius-2 ball (25 pts),
// zero-padded. Targets are binary -> bit-packed erosion (branchless, register-only).
// v4: 3 dispatches — pack (+ws zero via device atomics), main (R2-proven), finalize.
//     (R3's last-block ticket finalize removed: 1024-block single-address atomic
//      storm across XCDs was the suspect for the R2->R3 +17us regression.)

#define DD 128
#define HH 128
#define WW 128
#define HW_ (HH * WW)
#define DHW (DD * HH * WW)

typedef unsigned long long ull;

// ws layout: ws[0]=sum(bce) (double), ws[1]=sum(n) (double); packed bits at +256 B.

// ---------------- pass 1: pack targets (active channels) to 1 bit/voxel ----------------
// pk layout: pk[ch*32768 + row*2 + h], row = z*128+y, h selects x in [64h, 64h+64)
__global__ void __launch_bounds__(256) bal_pack(const float* __restrict__ targets,
                                                const int*   __restrict__ mask,
                                                ull*         __restrict__ pk,
                                                double*      __restrict__ ws)
{
    // one block zeroes the accumulators (device-scope atomics; visible to bal_main
    // via same-stream dispatch ordering)
    if (blockIdx.x == 0 && blockIdx.y == 0 && threadIdx.x == 0) {
        atomicExch((ull*)&ws[0], 0ull);
        atomicExch((ull*)&ws[1], 0ull);
    }

    const int ch = blockIdx.y;           // 0..7
    const int b  = ch >> 2;
    const int c  = (ch & 3) * 2 + 1;     // instance channels 1,3,5,7
    if (mask[b * 8 + c] == 0) return;

    const int tid = threadIdx.x;
    const size_t blockbase = (size_t)blockIdx.x * 1024;   // voxels
    const float* tg = targets + (size_t)(b * 8 + c) * DHW + blockbase;

    float4 t4 = *(const float4*)(tg + tid * 4);
    unsigned nib = (unsigned)(t4.x > 0.5f)
                 | ((unsigned)(t4.y > 0.5f) << 1)
                 | ((unsigned)(t4.z > 0.5f) << 2)
                 | ((unsigned)(t4.w > 0.5f) << 3);
    ull v = ((ull)nib) << ((tid & 15) * 4);
    // OR-combine nibbles across each aligned group of 16 lanes -> one u64 (64 voxels)
    v |= __shfl_xor(v, 1);
    v |= __shfl_xor(v, 2);
    v |= __shfl_xor(v, 4);
    v |= __shfl_xor(v, 8);
    if ((tid & 15) == 0)
        pk[(size_t)ch * 32768 + (blockbase >> 6) + (tid >> 4)] = v;
}

// ---------------- pass 2: erosion (bitwise) + BCE + reduction ----------------
__device__ __forceinline__ void ld_row(const ull* __restrict__ pch, int zz, int yy,
                                       ull& a0, ull& a1)
{
    if (((unsigned)zz < 128u) & ((unsigned)yy < 128u)) {
        const ull* p = pch + (((zz << 7) + yy) << 1);
        a0 = p[0];
        a1 = p[1];
    } else {
        a0 = 0ull;
        a1 = 0ull;
    }
}

__global__ void __launch_bounds__(256) bal_main(const float* __restrict__ logits,
                                                const float* __restrict__ spatial,
                                                const int*   __restrict__ mask,
                                                const ull*   __restrict__ pk,
                                                double*      __restrict__ ws)
{
    const int ch = blockIdx.y;
    const int b  = ch >> 2;
    const int c  = (ch & 3) * 2 + 1;
    if (mask[b * 8 + c] == 0) return;

    const int tid  = threadIdx.x;
    const int half = blockIdx.x * 256 + tid;   // 0..32767 half-rows (64 voxels each)
    const int row  = half >> 1;
    const int h    = half & 1;
    const int y    = row & 127;
    const int z    = row >> 7;
    const ull* pch = pk + (size_t)ch * 32768;

    // ---- branchless 25-pt erosion on 128-bit rows ----
    ull c0, c1;
    ld_row(pch, z, y, c0, c1);
    // center row: x-erosion radius 2
    ull elo = c0 & ((c0 >> 1) | (c1 << 63)) & (c0 << 1)
                 & ((c0 >> 2) | (c1 << 62)) & (c0 << 2);
    ull ehi = c1 & (c1 >> 1) & ((c1 << 1) | (c0 >> 63))
                 & (c1 >> 2) & ((c1 << 2) | (c0 >> 62));
    // Manhattan-dist-1 rows: radius 1
    {
        ull a0, a1;
        ld_row(pch, z - 1, y, a0, a1);
        elo &= a0 & ((a0 >> 1) | (a1 << 63)) & (a0 << 1);
        ehi &= a1 & (a1 >> 1) & ((a1 << 1) | (a0 >> 63));
        ld_row(pch, z + 1, y, a0, a1);
        elo &= a0 & ((a0 >> 1) | (a1 << 63)) & (a0 << 1);
        ehi &= a1 & (a1 >> 1) & ((a1 << 1) | (a0 >> 63));
        ld_row(pch, z, y - 1, a0, a1);
        elo &= a0 & ((a0 >> 1) | (a1 << 63)) & (a0 << 1);
        ehi &= a1 & (a1 >> 1) & ((a1 << 1) | (a0 >> 63));
        ld_row(pch, z, y + 1, a0, a1);
        elo &= a0 & ((a0 >> 1) | (a1 << 63)) & (a0 << 1);
        ehi &= a1 & (a1 >> 1) & ((a1 << 1) | (a0 >> 63));
    }
    // Manhattan-dist-2 rows: radius 0
    {
        ull a0, a1;
        ld_row(pch, z - 2, y,     a0, a1); elo &= a0; ehi &= a1;
        ld_row(pch, z + 2, y,     a0, a1); elo &= a0; ehi &= a1;
        ld_row(pch, z,     y - 2, a0, a1); elo &= a0; ehi &= a1;
        ld_row(pch, z,     y + 2, a0, a1); elo &= a0; ehi &= a1;
        ld_row(pch, z - 1, y - 1, a0, a1); elo &= a0; ehi &= a1;
        ld_row(pch, z - 1, y + 1, a0, a1); elo &= a0; ehi &= a1;
        ld_row(pch, z + 1, y - 1, a0, a1); elo &= a0; ehi &= a1;
        ld_row(pch, z + 1, y + 1, a0, a1); elo &= a0; ehi &= a1;
    }
    const ull ero   = h ? ehi : elo;
    const ull tbits = h ? c1  : c0;

    // ---- BCE: wave-cooperative, fully coalesced float4 streaming ----
    const int wave = tid >> 6;
    const int lane = tid & 63;
    const float* lg = logits  + (size_t)(b * 8 + c) * DHW;
    const float* sp = spatial + (size_t)b * DHW;
    const int    waveHalfBase = blockIdx.x * 256 + wave * 64;
    const size_t vbase        = (size_t)waveHalfBase * 64;

    float acc = 0.0f, n = 0.0f;
    #pragma unroll 4
    for (int m = 0; m < 16; ++m) {
        const int q   = 4 * m + (lane >> 4);   // half-row (within wave) this lane serves
        const ull er  = __shfl(ero, q);
        const ull tb  = __shfl(tbits, q);
        const int sh  = (lane & 15) * 4;
        const unsigned eb  = (unsigned)(er >> sh) & 0xFu;
        const unsigned tbn = (unsigned)(tb >> sh) & 0xFu;
        const size_t voff = vbase + (size_t)q * 64 + sh;   // == vbase + 256*m + lane*4
        const float4 l4 = *(const float4*)(lg + voff);
        const float4 s4 = *(const float4*)(sp + voff);
        #define PROC(LV, SV, TB, EB)                                              \
        {                                                                         \
            const float tf = (float)(TB);                                         \
            const float w  = fmaf(4.0f, tf - (float)(EB), 1.0f);                  \
            const float a  = fabsf(LV);                                           \
            const float u  = __builtin_amdgcn_exp2f(a * -1.4426950408889634f);    \
            const float so = __builtin_amdgcn_logf(1.0f + u) * 0.6931471805599453f;\
            const float bce = fmaxf(LV, 0.0f) - (LV) * tf + so;                   \
            acc = fmaf((SV) * w, bce, acc);                                       \
            n += (SV);                                                            \
        }
        PROC(l4.x, s4.x, tbn & 1u,        eb & 1u)
        PROC(l4.y, s4.y, (tbn >> 1) & 1u, (eb >> 1) & 1u)
        PROC(l4.z, s4.z, (tbn >> 2) & 1u, (eb >> 2) & 1u)
        PROC(l4.w, s4.w, (tbn >> 3) & 1u, (eb >> 3) & 1u)
        #undef PROC
    }

    // wave (64-lane) shuffle reduction
    #pragma unroll
    for (int o = 32; o > 0; o >>= 1) {
        acc += __shfl_down(acc, o);
        n   += __shfl_down(n, o);
    }
    __shared__ float sb[4], sn[4];
    if (lane == 0) { sb[wave] = acc; sn[wave] = n; }
    __syncthreads();
    if (tid == 0) {
        atomicAdd(&ws[0], (double)(sb[0] + sb[1] + sb[2] + sb[3]));
        atomicAdd(&ws[1], (double)(sn[0] + sn[1] + sn[2] + sn[3]));
    }
}

// ---------------- fallback (ws too small): round-1 direct kernel ----------------
__device__ __constant__ signed char OFFS[24][3] = {
    {-1,0,0},{1,0,0},{0,-1,0},{0,1,0},{0,0,-1},{0,0,1},
    {-2,0,0},{2,0,0},{0,-2,0},{0,2,0},{0,0,-2},{0,0,2},
    {-1,-1,0},{-1,1,0},{1,-1,0},{1,1,0},
    {-1,0,-1},{-1,0,1},{1,0,-1},{1,0,1},
    {0,-1,-1},{0,-1,1},{0,1,-1},{0,1,1}
};

__global__ void __launch_bounds__(256) bal_direct(
    const float* __restrict__ logits, const float* __restrict__ targets,
    const int* __restrict__ mask, const float* __restrict__ spatial,
    double* __restrict__ ws)
{
    const int ch = blockIdx.y;
    const int b  = ch >> 2;
    const int c  = 2 * (ch & 3) + 1;
    if (mask[b * 8 + c] == 0) return;
    const float* lg = logits  + (size_t)(b * 8 + c) * DHW;
    const float* tg = targets + (size_t)(b * 8 + c) * DHW;
    const float* sp = spatial + (size_t)b * DHW;
    const int tid = threadIdx.x;
    const int row = blockIdx.x * 8 + (tid >> 5);
    const int x0  = (tid & 31) * 4;
    const int z   = row >> 7;
    const int y   = row & 127;
    const size_t off = (size_t)row * WW + x0;
    float4 s4 = *(const float4*)(sp + off);
    float n_local   = s4.x + s4.y + s4.z + s4.w;
    float bce_local = 0.0f;
    if (n_local > 0.0f) {
        float4 l4 = *(const float4*)(lg + off);
        float4 t4 = *(const float4*)(tg + off);
        const float sv[4] = {s4.x, s4.y, s4.z, s4.w};
        const float lv[4] = {l4.x, l4.y, l4.z, l4.w};
        const float tv[4] = {t4.x, t4.y, t4.z, t4.w};
        #pragma unroll
        for (int j = 0; j < 4; ++j) {
            if (sv[j] == 0.0f) continue;
            const float l = lv[j];
            const float t = tv[j];
            float bce = fmaxf(l, 0.0f) - l * t + log1pf(expf(-fabsf(l)));
            float w = 1.0f;
            if (t > 0.5f) {
                float e = 1.0f;
                const int x = x0 + j;
                for (int k = 0; k < 24; ++k) {
                    const int zz = z + OFFS[k][0];
                    const int yy = y + OFFS[k][1];
                    const int xx = x + OFFS[k][2];
                    float v = 0.0f;
                    if (((unsigned)zz < 128u) & ((unsigned)yy < 128u) & ((unsigned)xx < 128u))
                        v = tg[zz * HW_ + yy * WW + xx];
                    if (v < 0.5f) { e = 0.0f; break; }
                }
                w = 1.0f + 4.0f * (1.0f - e);
            }
            bce_local += bce * w;
        }
    }
    #pragma unroll
    for (int o = 32; o > 0; o >>= 1) {
        bce_local += __shfl_down(bce_local, o);
        n_local   += __shfl_down(n_local, o);
    }
    __shared__ float sb[4], sn[4];
    const int wave = tid >> 6;
    if ((tid & 63) == 0) { sb[wave] = bce_local; sn[wave] = n_local; }
    __syncthreads();
    if (tid == 0) {
        atomicAdd(&ws[0], (double)(sb[0] + sb[1] + sb[2] + sb[3]));
        atomicAdd(&ws[1], (double)(sn[0] + sn[1] + sn[2] + sn[3]));
    }
}

__global__ void bal_finalize(const double* __restrict__ ws, float* __restrict__ out)
{
    const double s = ws[0];
    const double n = ws[1];
    out[0] = (n > 0.0) ? (float)(s / (n < 1.0 ? 1.0 : n)) : 0.0f;
}

extern "C" void kernel_launch(void* const* d_in, const int* in_sizes, int n_in,
                              void* d_out, int out_size, void* d_ws, size_t ws_size,
                              hipStream_t stream)
{
    const float* logits  = (const float*)d_in[0];
    const float* targets = (const float*)d_in[1];
    const int*   mask    = (const int*)d_in[2];
    const float* spatial = (const float*)d_in[3];
    double* ws = (double*)d_ws;

    const size_t need = 256 + (size_t)8 * 32768 * sizeof(ull);   // sums pad + 2 MB bits
    if (ws_size >= need) {
        ull* pk = (ull*)((char*)d_ws + 256);
        bal_pack<<<dim3(2048, 8), 256, 0, stream>>>(targets, mask, pk, ws);
        bal_main<<<dim3(128, 8), 256, 0, stream>>>(logits, spatial, mask, pk, ws);
    } else {
        hipMemsetAsync(d_ws, 0, 16, stream);
        bal_direct<<<dim3(2048, 8), 256, 0, stream>>>(logits, targets, mask, spatial, ws);
    }
    bal_finalize<<<1, 1, 0, stream>>>(ws, (float*)d_out);
}